// Round 4
// baseline (1354.942 us; speedup 1.0000x reference)
//
#include <hip/hip_runtime.h>
#include <math.h>

#define H      2048
#define HV4    512          // float4 per token row
#define E      64
#define T_TOK  32768
#define KS4    128          // float4 per wave k-slice (512 floats); 4 waves cover H
#define KC4    8            // float4 per chunk per token (KC = 32 floats)
#define NCH    16           // chunks per slice
#define GATES_OFF   0
#define IDX_OFF     65536
#define LOSS_OFF    131072

// ---- W transpose: W[e][h] -> Wt[h/4][e][4]; also zero-inits accum ----
__global__ void transpose_w_kernel(const float* __restrict__ W, float* __restrict__ Wt,
                                   float* __restrict__ accum) {
    int id = blockIdx.x * 256 + threadIdx.x;       // 131072 total
    if (blockIdx.x == 0 && threadIdx.x < 128) accum[threadIdx.x] = 0.f;
    int e = id >> 11;
    int h = id & 2047;
    Wt[(h >> 2) * 256 + (e << 2) + (h & 3)] = W[id];
}

// ---------------- main gating kernel ----------------
// Block: 256 thr / 4 waves. Block owns 64 tokens; wave w owns k-slice [w*512,(w+1)*512).
// lane = token. acc[64] = logit partial for ALL experts of this lane's token.
// W is wave-uniform -> SGPR operand in v_fma (no LDS/vector traffic).
// X: coalesced global -> regs -> swizzled LDS tile -> ONE per-lane ds_read_b128 per k4
// (reused by 256 FMAs; R3's 64-way broadcast replication eliminated).
__global__ __launch_bounds__(256) void gate_main_kernel(
        const float4* __restrict__ x4,       // (T, HV4)
        const float4* __restrict__ wt4,      // [512][E] float4
        float* __restrict__ out,
        float* __restrict__ accum)           // [0:64) sum probs, [64:128) counts
{
    __shared__ float4 lds[4096];             // 64 KB: X tiles, then reused as P[4][64][16]f4

    const int tid  = threadIdx.x;
    const int lane = tid & 63;
    const int w    = __builtin_amdgcn_readfirstlane(tid >> 6);  // wave id (uniform)
    const int tokBase = blockIdx.x * 64;
    const int kbase4  = w * KS4;             // uniform k-slice base (float4 units)

    float acc[E];
#pragma unroll
    for (int e = 0; e < E; ++e) acc[e] = 0.f;

    float4* xt = &lds[w * 1024];             // this wave's 2 buffers of 512 float4

    const int stok = lane >> 3;              // staging: token sub-index
    const int sk4  = lane & 7;               // staging: k4 within chunk

    float4 xbuf[8];

    // chunk c global loads -> xbuf (8 coalesced dwordx4 per lane, 8 full lines/instr)
    auto g_load = [&](int c) {
#pragma unroll
        for (int j = 0; j < 8; ++j) {
            int tok = j * 8 + stok;
            xbuf[j] = x4[(size_t)(tokBase + tok) * HV4 + kbase4 + c * KC4 + sk4];
        }
    };
    // xbuf -> LDS buffer (c&1), XOR-swizzled columns (conflict-free, no padding)
    auto l_store = [&](int c) {
        float4* dst = xt + (c & 1) * 512;
#pragma unroll
        for (int j = 0; j < 8; ++j) {
            int tok = j * 8 + stok;
            dst[tok * 8 + (sk4 ^ (tok & 7))] = xbuf[j];
        }
    };

    auto compute = [&](int c) {
        const float4* src = xt + (c & 1) * 512 + lane * 8;
        const int swz = lane & 7;
        const float4* wrow = wt4 + (size_t)(kbase4 + c * KC4) * E;   // uniform
#pragma unroll 2
        for (int k4 = 0; k4 < KC4; ++k4) {
            float4 xv = src[k4 ^ swz];       // per-lane distinct, 8-phase min, reused 256x
            const float4* wp = wrow + k4 * E;
#pragma unroll
            for (int e = 0; e < E; ++e) {
                float4 wv = wp[e];           // uniform -> s_load, SGPR FMA operand
                acc[e] = fmaf(xv.x, wv.x, acc[e]);
                acc[e] = fmaf(xv.y, wv.y, acc[e]);
                acc[e] = fmaf(xv.z, wv.z, acc[e]);
                acc[e] = fmaf(xv.w, wv.w, acc[e]);
            }
        }
    };

    // barrier-free double-buffered K loop (waves own disjoint LDS regions)
    g_load(0);
    l_store(0);
    for (int c = 0; c < NCH; ++c) {
        if (c + 1 < NCH) g_load(c + 1);      // ~900cy latency hides under ~4096cy FMA
        compute(c);
        if (c + 1 < NCH) l_store(c + 1);
    }

    // ---------- epilogue: combine 4 k-slice partials, softmax, top2, aux sums ----------
    __syncthreads();                         // all waves done; X tiles reusable
    float4* P = lds;                         // P[s][tok][e4] : (s*64+tok)*16 + e4
    {
        float4* dst = &P[(w * 64 + lane) * 16];
#pragma unroll
        for (int e4 = 0; e4 < 16; ++e4)
            dst[e4] = make_float4(acc[4*e4], acc[4*e4+1], acc[4*e4+2], acc[4*e4+3]);
    }
    __syncthreads();

    const int tl  = lane >> 2;               // 0..15: token within this wave's sub-slab
    const int eq  = lane & 3;                // expert quarter
    const int tok = tokBase + w * 16 + tl;
    const int prow = w * 16 + tl;            // token local to block

    float l16[16];
#pragma unroll
    for (int j4 = 0; j4 < 4; ++j4) {
        float4 s0 = P[(0 * 64 + prow) * 16 + eq * 4 + j4];
        float4 s1 = P[(1 * 64 + prow) * 16 + eq * 4 + j4];
        float4 s2 = P[(2 * 64 + prow) * 16 + eq * 4 + j4];
        float4 s3 = P[(3 * 64 + prow) * 16 + eq * 4 + j4];
        l16[4*j4+0] = s0.x + s1.x + s2.x + s3.x;
        l16[4*j4+1] = s0.y + s1.y + s2.y + s3.y;
        l16[4*j4+2] = s0.z + s1.z + s2.z + s3.z;
        l16[4*j4+3] = s0.w + s1.w + s2.w + s3.w;
    }

    // softmax over 64 experts: 16 in-register + quad reduce (lanes 4t..4t+3)
    float m = l16[0];
#pragma unroll
    for (int j = 1; j < 16; ++j) m = fmaxf(m, l16[j]);
    m = fmaxf(m, __shfl_xor(m, 1));
    m = fmaxf(m, __shfl_xor(m, 2));
    float ex[16], ssum = 0.f;
#pragma unroll
    for (int j = 0; j < 16; ++j) { ex[j] = expf(l16[j] - m); ssum += ex[j]; }
    ssum += __shfl_xor(ssum, 1);
    ssum += __shfl_xor(ssum, 2);
    const float inv = 1.f / ssum;

    float sP[16], sC[16];
#pragma unroll
    for (int j = 0; j < 16; ++j) {
        float p = ex[j] * inv;
        sP[j] = p;
        sC[j] = (p > 0.f) ? 1.f : 0.f;
    }
    // reduce over the wave's 16 tokens (lanes differing in bits 2..5)
#pragma unroll
    for (int j = 0; j < 16; ++j) {
#pragma unroll
        for (int d = 4; d <= 32; d <<= 1) {
            sP[j] += __shfl_xor(sP[j], d);
            sC[j] += __shfl_xor(sC[j], d);
        }
    }
    if (lane < 4) {                          // lane == eq here
#pragma unroll
        for (int j = 0; j < 16; ++j) {
            atomicAdd(&accum[eq * 16 + j], sP[j]);
            atomicAdd(&accum[E + eq * 16 + j], sC[j]);
        }
    }

    // top-2 with lower-index tie-break: local chain over 16, then quad tournament
    float v1 = l16[0]; int i1 = eq * 16;
    float v2 = -INFINITY; int i2 = -1;
#pragma unroll
    for (int j = 1; j < 16; ++j) {
        float v = l16[j]; int e = eq * 16 + j;
        if (v > v1)      { v2 = v1; i2 = i1; v1 = v; i1 = e; }
        else if (v > v2) { v2 = v; i2 = e; }
    }
#pragma unroll
    for (int d = 1; d <= 2; d <<= 1) {       // self = A (lower expert ids), partner = B
        float bv1 = __shfl_down(v1, d); int bi1 = __shfl_down(i1, d);
        float bv2 = __shfl_down(v2, d); int bi2 = __shfl_down(i2, d);
        if (bv1 > v1) {
            if (bv2 > v1) { v2 = bv2; i2 = bi2; } else { v2 = v1; i2 = i1; }  // tie -> A
            v1 = bv1; i1 = bi1;
        } else {                              // tie on top1 -> A keeps (lower idx)
            if (bv1 > v2) { v2 = bv1; i2 = bi1; }                             // tie -> A
        }
    }
    if (eq == 0) {
        float t  = expf(v2 - v1);
        float g1 = 1.f / (1.f + t);
        out[GATES_OFF + 2 * tok]     = g1;
        out[GATES_OFF + 2 * tok + 1] = t * g1;
        out[IDX_OFF   + 2 * tok]     = (float)i1;
        out[IDX_OFF   + 2 * tok + 1] = (float)i2;
    }
}

// ---------------- final loss kernel ----------------
__global__ void gate_final_kernel(const float* __restrict__ accum, float* __restrict__ out) {
    int lane = threadIdx.x;                  // 64 threads
    const float invT = 1.f / (float)T_TOK;
    float mean_p  = accum[lane] * invT;
    float routing = accum[E + lane] * invT;
    float term = mean_p * routing;
#pragma unroll
    for (int d = 32; d > 0; d >>= 1) term += __shfl_xor(term, d, 64);
    if (lane == 0) out[LOSS_OFF] = 64.f * term;
}

extern "C" void kernel_launch(void* const* d_in, const int* in_sizes, int n_in,
                              void* d_out, int out_size, void* d_ws, size_t ws_size,
                              hipStream_t stream) {
    const float* x = (const float*)d_in[0];   // (4,8192,2048) fp32
    const float* W = (const float*)d_in[1];   // (64,2048) fp32
    float* out   = (float*)d_out;
    float* accum = (float*)d_ws;              // 128 floats
    float* Wt    = (float*)d_ws + 128;        // 131072 floats (16B-aligned)

    transpose_w_kernel<<<512, 256, 0, stream>>>(W, Wt, accum);
    gate_main_kernel<<<T_TOK / 64, 256, 0, stream>>>((const float4*)x, (const float4*)Wt, out, accum);
    gate_final_kernel<<<1, 64, 0, stream>>>(accum, out);
}

// Round 5
// 1147.181 us; speedup vs baseline: 1.1811x; 1.1811x over previous
//
#include <hip/hip_runtime.h>
#include <math.h>

#define H      2048
#define HV4    512          // float4 per token row
#define E      64
#define T_TOK  32768
#define NCH    32           // chunks per wave k-slice (512 / 16)
#define GATES_OFF   0
#define IDX_OFF     65536
#define LOSS_OFF    131072

// ---- W transpose: W[e][h] -> Wt[h][e] (coalesced writes); zero-inits accum ----
__global__ void transpose_w_kernel(const float* __restrict__ W, float* __restrict__ Wt,
                                   float* __restrict__ accum) {
    int id = blockIdx.x * 256 + threadIdx.x;       // 131072 total
    if (blockIdx.x == 0 && threadIdx.x < 128) accum[threadIdx.x] = 0.f;
    int h = id >> 6;
    int e = id & 63;
    Wt[id] = W[e * H + h];                          // Wt[h*64+e], writes coalesced
}

// ---------------- main gating kernel ----------------
// C[64 tok x 64 exp] per block. 4 waves split K (512 each), barrier-free K-loop
// (disjoint LDS). Thread tile 8x8: per k, 4 per-lane-distinct ds_read_b128 feed
// 64 v_fma (ratio 16:1 vs R3's 4:1 -> VALU-bound, not LDS-return-bound).
// acc[8][8]=64 VGPR + no SGPR-resident W => no spill (R4's killer).
__global__ __launch_bounds__(256) void gate_main_kernel(
        const float4* __restrict__ x4,       // (T, HV4)
        const float4* __restrict__ wt4,      // Wt[h][e] as float4: [h][e4]
        float* __restrict__ out,
        float* __restrict__ accum)           // [0:64) sum probs, [64:128) counts
{
    __shared__ float lds[16384];             // 64 KB: K-loop tiles, then P[4][64][64]

    const int tid  = threadIdx.x;
    const int lane = tid & 63;
    const int w    = __builtin_amdgcn_readfirstlane(tid >> 6);
    const int tokBase = blockIdx.x * 64;
    const int tm = lane >> 3;                // token group (8 tokens tm*8..+7)
    const int tn = lane & 7;                 // expert group (8 experts tn*8..+7)

    float* xt = lds + w * 2048;              // [2][16][64] : At[k][tok], per-wave
    float* bt = lds + 8192 + w * 2048;       // [2][16][64] : Bt[k][e],  per-wave
    float4* bt4 = (float4*)bt;

    float acc[8][8] = {};

    // staging decomposition: f4 = j*64+lane -> tok=f4/4, kq=f4%4
    const int stok = lane >> 2;              // 0..15
    const int skq  = lane & 3;               // 0..3
    const float4* xg = x4 + (size_t)tokBase * HV4 + (size_t)w * 128 + skq;
    const float4* wg = wt4 + (size_t)w * 8192;   // wave k-slice base (f4 units)

    float4 xb[4], wb[4];

    auto g_load = [&](int c) {               // 4 X + 4 W coalesced dwordx4 per lane
#pragma unroll
        for (int j = 0; j < 4; ++j) {
            int tok = j * 16 + stok;
            xb[j] = xg[(size_t)tok * HV4 + c * 4];
            wb[j] = wg[c * 256 + j * 64 + lane];
        }
    };
    auto l_store = [&](int c) {
        int b = c & 1;
        float* xdst = xt + b * 1024;
#pragma unroll
        for (int j = 0; j < 4; ++j) {
            int tok = j * 16 + stok;         // transpose scatter: At[k][tok]
            xdst[(skq * 4 + 0) * 64 + tok] = xb[j].x;
            xdst[(skq * 4 + 1) * 64 + tok] = xb[j].y;
            xdst[(skq * 4 + 2) * 64 + tok] = xb[j].z;
            xdst[(skq * 4 + 3) * 64 + tok] = xb[j].w;
            bt4[b * 256 + j * 64 + lane] = wb[j];   // straight copy Bt[k][e]
        }
    };
    auto compute = [&](int c) {
        const float* xa = xt + (c & 1) * 1024 + tm * 8;
        const float* ba = bt + (c & 1) * 1024 + tn * 8;
#pragma unroll 4
        for (int k = 0; k < 16; ++k) {
            float4 a0 = *(const float4*)(xa + k * 64);
            float4 a1 = *(const float4*)(xa + k * 64 + 4);
            float4 b0 = *(const float4*)(ba + k * 64);
            float4 b1 = *(const float4*)(ba + k * 64 + 4);
            float av[8] = {a0.x, a0.y, a0.z, a0.w, a1.x, a1.y, a1.z, a1.w};
            float bv[8] = {b0.x, b0.y, b0.z, b0.w, b1.x, b1.y, b1.z, b1.w};
#pragma unroll
            for (int i = 0; i < 8; ++i)
#pragma unroll
                for (int jj = 0; jj < 8; ++jj)
                    acc[i][jj] = fmaf(av[i], bv[jj], acc[i][jj]);
        }
    };

    g_load(0);
    l_store(0);
    for (int c = 0; c < NCH; ++c) {
        if (c + 1 < NCH) g_load(c + 1);      // VMEM latency hides under 64x16 FMAs
        compute(c);
        if (c + 1 < NCH) l_store(c + 1);     // writes buf c^1 while c was read
    }

    // ---------- epilogue: combine 4 k-slice partials, softmax, top2, aux ----------
    __syncthreads();                         // all waves done; reuse LDS as P
    float4* P = (float4*)lds;                // P[(s*64 + t)*16 + e4]
#pragma unroll
    for (int i = 0; i < 8; ++i) {
        int row = (w * 64 + tm * 8 + i) * 16 + tn * 2;
        P[row]     = make_float4(acc[i][0], acc[i][1], acc[i][2], acc[i][3]);
        P[row + 1] = make_float4(acc[i][4], acc[i][5], acc[i][6], acc[i][7]);
    }
    __syncthreads();

    const int tl  = lane >> 2;               // 0..15: token within wave's sub-slab
    const int eq  = lane & 3;                // expert quarter
    const int tok = tokBase + w * 16 + tl;
    const int prow = w * 16 + tl;

    float l16[16];
#pragma unroll
    for (int j4 = 0; j4 < 4; ++j4) {
        float4 s0 = P[(0 * 64 + prow) * 16 + eq * 4 + j4];
        float4 s1 = P[(1 * 64 + prow) * 16 + eq * 4 + j4];
        float4 s2 = P[(2 * 64 + prow) * 16 + eq * 4 + j4];
        float4 s3 = P[(3 * 64 + prow) * 16 + eq * 4 + j4];
        l16[4*j4+0] = s0.x + s1.x + s2.x + s3.x;
        l16[4*j4+1] = s0.y + s1.y + s2.y + s3.y;
        l16[4*j4+2] = s0.z + s1.z + s2.z + s3.z;
        l16[4*j4+3] = s0.w + s1.w + s2.w + s3.w;
    }

    // softmax over 64 experts: 16 in-register + quad reduce
    float m = l16[0];
#pragma unroll
    for (int j = 1; j < 16; ++j) m = fmaxf(m, l16[j]);
    m = fmaxf(m, __shfl_xor(m, 1));
    m = fmaxf(m, __shfl_xor(m, 2));
    float ex[16], ssum = 0.f;
#pragma unroll
    for (int j = 0; j < 16; ++j) { ex[j] = expf(l16[j] - m); ssum += ex[j]; }
    ssum += __shfl_xor(ssum, 1);
    ssum += __shfl_xor(ssum, 2);
    const float inv = 1.f / ssum;

    float sP[16], sC[16];
#pragma unroll
    for (int j = 0; j < 16; ++j) {
        float p = ex[j] * inv;
        sP[j] = p;
        sC[j] = (p > 0.f) ? 1.f : 0.f;
    }
#pragma unroll
    for (int j = 0; j < 16; ++j) {
#pragma unroll
        for (int d = 4; d <= 32; d <<= 1) {
            sP[j] += __shfl_xor(sP[j], d);
            sC[j] += __shfl_xor(sC[j], d);
        }
    }
    if (lane < 4) {                          // lane == eq here
#pragma unroll
        for (int j = 0; j < 16; ++j) {
            atomicAdd(&accum[eq * 16 + j], sP[j]);
            atomicAdd(&accum[E + eq * 16 + j], sC[j]);
        }
    }

    // top-2 with lower-index tie-break: local chain over 16, then quad tournament
    float v1 = l16[0]; int i1 = eq * 16;
    float v2 = -INFINITY; int i2 = -1;
#pragma unroll
    for (int j = 1; j < 16; ++j) {
        float v = l16[j]; int e = eq * 16 + j;
        if (v > v1)      { v2 = v1; i2 = i1; v1 = v; i1 = e; }
        else if (v > v2) { v2 = v; i2 = e; }
    }
#pragma unroll
    for (int d = 1; d <= 2; d <<= 1) {       // self = A (lower expert ids)
        float bv1 = __shfl_down(v1, d); int bi1 = __shfl_down(i1, d);
        float bv2 = __shfl_down(v2, d); int bi2 = __shfl_down(i2, d);
        if (bv1 > v1) {
            if (bv2 > v1) { v2 = bv2; i2 = bi2; } else { v2 = v1; i2 = i1; }
            v1 = bv1; i1 = bi1;
        } else {
            if (bv1 > v2) { v2 = bv1; i2 = bi1; }
        }
    }
    if (eq == 0) {
        float t  = expf(v2 - v1);
        float g1 = 1.f / (1.f + t);
        out[GATES_OFF + 2 * tok]     = g1;
        out[GATES_OFF + 2 * tok + 1] = t * g1;
        out[IDX_OFF   + 2 * tok]     = (float)i1;
        out[IDX_OFF   + 2 * tok + 1] = (float)i2;
    }
}

// ---------------- final loss kernel ----------------
__global__ void gate_final_kernel(const float* __restrict__ accum, float* __restrict__ out) {
    int lane = threadIdx.x;                  // 64 threads
    const float invT = 1.f / (float)T_TOK;
    float mean_p  = accum[lane] * invT;
    float routing = accum[E + lane] * invT;
    float term = mean_p * routing;
#pragma unroll
    for (int d = 32; d > 0; d >>= 1) term += __shfl_xor(term, d, 64);
    if (lane == 0) out[LOSS_OFF] = 64.f * term;
}

extern "C" void kernel_launch(void* const* d_in, const int* in_sizes, int n_in,
                              void* d_out, int out_size, void* d_ws, size_t ws_size,
                              hipStream_t stream) {
    const float* x = (const float*)d_in[0];   // (4,8192,2048) fp32
    const float* W = (const float*)d_in[1];   // (64,2048) fp32
    float* out   = (float*)d_out;
    float* accum = (float*)d_ws;              // 128 floats
    float* Wt    = (float*)d_ws + 128;        // 131072 floats (16B-aligned)

    transpose_w_kernel<<<512, 256, 0, stream>>>(W, Wt, accum);
    gate_main_kernel<<<T_TOK / 64, 256, 0, stream>>>((const float4*)x, (const float4*)Wt, out, accum);
    gate_final_kernel<<<1, 64, 0, stream>>>(accum, out);
}